// Round 1
// baseline (75.612 us; speedup 1.0000x reference)
//
#include <hip/hip_runtime.h>
#include <math.h>

// Distance kernel: out[b,n,m,{cos,p1,p2}] for x[B,N,D], y[M,D], D=128.
// Flatten (b,n) -> R rows. Compute-bound on vector fp32 (no fp32 MFMA on CDNA4).
// Block tile: 32 n-rows x 64 m-rows; thread tile 2x4; LDS staging, rows padded
// to 132 floats so lane-stride ds_read_b128 is bank-conflict-free.

#define DDIM 128
#define BN 32
#define BM 64
#define TN 2
#define TM 4
#define PADW 132   // floats per LDS row (128 + 4 pad): stride mod 32 = 4 banks

__global__ __launch_bounds__(256, 2) void distance_kernel(
    const float* __restrict__ x, const float* __restrict__ y,
    float* __restrict__ out, int R, int M)
{
    __shared__ float xs[BN * PADW];
    __shared__ float ys[BM * PADW];
    __shared__ float xrn[BN];
    __shared__ float yrn[BM];

    const int t  = threadIdx.x;
    const int n0 = blockIdx.x * BN;
    const int m0 = blockIdx.y * BM;

    // ---- Stage x tile (32 rows x 32 float4) and y tile (64 x 32 float4) ----
    {
        const float4* xg = (const float4*)(x + (size_t)n0 * DDIM);
        #pragma unroll
        for (int k = 0; k < (BN * DDIM / 4) / 256; ++k) {   // 4 iters
            int idx = t + 256 * k;
            int row = idx >> 5;
            int c   = idx & 31;
            float4 v = xg[(row << 5) + c];
            *(float4*)&xs[row * PADW + (c << 2)] = v;
        }
        const float4* yg = (const float4*)(y + (size_t)m0 * DDIM);
        #pragma unroll
        for (int k = 0; k < (BM * DDIM / 4) / 256; ++k) {   // 8 iters
            int idx = t + 256 * k;
            int row = idx >> 5;
            int c   = idx & 31;
            float4 v = yg[(row << 5) + c];
            *(float4*)&ys[row * PADW + (c << 2)] = v;
        }
    }
    __syncthreads();

    // ---- Cooperative row rsqrt-norms (cos normalization, O(rows) not O(pairs))
    if (t < BN) {
        float s = 0.f;
        const float4* r = (const float4*)&xs[t * PADW];
        #pragma unroll
        for (int c = 0; c < DDIM / 4; ++c) {
            float4 v = r[c];
            s += v.x * v.x + v.y * v.y + v.z * v.z + v.w * v.w;
        }
        xrn[t] = rsqrtf(s);
    } else if (t >= 64 && t < 64 + BM) {
        int row = t - 64;
        float s = 0.f;
        const float4* r = (const float4*)&ys[row * PADW];
        #pragma unroll
        for (int c = 0; c < DDIM / 4; ++c) {
            float4 v = r[c];
            s += v.x * v.x + v.y * v.y + v.z * v.z + v.w * v.w;
        }
        yrn[row] = rsqrtf(s);
    }
    __syncthreads();

    // ---- Main loop: thread (ln, lm) handles n = n0+ln+16i, m = m0+lm+16j ----
    const int lm = t & 15;
    const int ln = t >> 4;

    float dot[TN][TM] = {};
    float p1 [TN][TM] = {};
    float p2 [TN][TM] = {};

    #pragma unroll 4
    for (int c = 0; c < DDIM / 4; ++c) {
        float4 xv[TN], yv[TM];
        #pragma unroll
        for (int i = 0; i < TN; ++i)
            xv[i] = *(const float4*)&xs[(ln + 16 * i) * PADW + (c << 2)];
        #pragma unroll
        for (int j = 0; j < TM; ++j)
            yv[j] = *(const float4*)&ys[(lm + 16 * j) * PADW + (c << 2)];

        #pragma unroll
        for (int i = 0; i < TN; ++i) {
            #pragma unroll
            for (int j = 0; j < TM; ++j) {
                float d0 = xv[i].x - yv[j].x;
                float d1 = xv[i].y - yv[j].y;
                float d2 = xv[i].z - yv[j].z;
                float d3 = xv[i].w - yv[j].w;
                p1[i][j] += fabsf(d0); p2[i][j] = fmaf(d0, d0, p2[i][j]);
                dot[i][j] = fmaf(xv[i].x, yv[j].x, dot[i][j]);
                p1[i][j] += fabsf(d1); p2[i][j] = fmaf(d1, d1, p2[i][j]);
                dot[i][j] = fmaf(xv[i].y, yv[j].y, dot[i][j]);
                p1[i][j] += fabsf(d2); p2[i][j] = fmaf(d2, d2, p2[i][j]);
                dot[i][j] = fmaf(xv[i].z, yv[j].z, dot[i][j]);
                p1[i][j] += fabsf(d3); p2[i][j] = fmaf(d3, d3, p2[i][j]);
                dot[i][j] = fmaf(xv[i].w, yv[j].w, dot[i][j]);
            }
        }
    }

    // ---- Epilogue: out[(n*M + m)*3 + {0,1,2}] ----
    #pragma unroll
    for (int i = 0; i < TN; ++i) {
        int n = n0 + ln + 16 * i;
        float xr = xrn[ln + 16 * i];
        #pragma unroll
        for (int j = 0; j < TM; ++j) {
            int m = m0 + lm + 16 * j;
            float* o = out + ((size_t)n * M + m) * 3;
            o[0] = dot[i][j] * xr * yrn[lm + 16 * j];
            o[1] = p1[i][j];
            o[2] = sqrtf(p2[i][j]);
        }
    }
}

extern "C" void kernel_launch(void* const* d_in, const int* in_sizes, int n_in,
                              void* d_out, int out_size, void* d_ws, size_t ws_size,
                              hipStream_t stream) {
    const float* x = (const float*)d_in[0];
    const float* y = (const float*)d_in[1];
    float* out = (float*)d_out;

    const int R = in_sizes[0] / DDIM;   // B*N = 2048
    const int M = in_sizes[1] / DDIM;   // 512

    dim3 grid(R / BN, M / BM);          // (64, 8) = 512 blocks
    distance_kernel<<<grid, 256, 0, stream>>>(x, y, out, R, M);
}